// Round 2
// baseline (1592.416 us; speedup 1.0000x reference)
//
#include <hip/hip_runtime.h>
#include <hip/hip_bf16.h>
#include <math.h>

using bf16 = __hip_bfloat16;
typedef __attribute__((ext_vector_type(8))) short short8;
typedef __attribute__((ext_vector_type(4))) short shortx4;
typedef __attribute__((ext_vector_type(4))) float floatx4;

// Problem constants
#define BB 16
#define NN 1024
#define DD 768
#define HH 12
#define HD 64
#define HID 3072

__device__ __forceinline__ floatx4 mfma_bf16(short8 a, short8 b, floatx4 c) {
  return __builtin_amdgcn_mfma_f32_16x16x32_bf16(a, b, c, 0, 0, 0);
}

__device__ __forceinline__ short bf16_bits(float f) {
  union { bf16 h; short s; } u;
  u.h = __float2bfloat16(f);
  return u.s;
}

__device__ __forceinline__ void async_copy16(const void* g, void* l) {
  __builtin_amdgcn_global_load_lds(
      (const __attribute__((address_space(1))) unsigned int*)g,
      (__attribute__((address_space(3))) unsigned int*)l,
      16, 0, 0);
}

// tanh-form gelu via exp2 (verified absmax-equal last round)
__device__ __forceinline__ float gelu_f(float x) {
  const float z = x * fmaf(0.10294324f, x * x, 2.3022082f);
  const float e = exp2f(z);
  return x - x * __builtin_amdgcn_rcpf(e + 1.0f);
}

// ---------------------------------------------------------------------------
// fp32 -> bf16 conversion (weights), 4 elements/thread.
// ---------------------------------------------------------------------------
__global__ __launch_bounds__(256)
void cvt_kernel(const float* __restrict__ in, bf16* __restrict__ out, int n4)
{
  const int i = blockIdx.x * 256 + threadIdx.x;
  if (i >= n4) return;
  const float4 v = ((const float4*)in)[i];
  shortx4 o;
  o.x = bf16_bits(v.x); o.y = bf16_bits(v.y);
  o.z = bf16_bits(v.z); o.w = bf16_bits(v.w);
  ((shortx4*)out)[i] = o;
}

// ---------------------------------------------------------------------------
// LayerNorm: fp32 in, bf16 out. One block (256 thr) per row of 768.
// ---------------------------------------------------------------------------
__global__ __launch_bounds__(256)
void ln_kernel(const float* __restrict__ x, const float* __restrict__ g,
               const float* __restrict__ b, bf16* __restrict__ y)
{
  const int row = blockIdx.x;
  const int t = threadIdx.x;
  const float* xr = x + (size_t)row * DD;
  float v[3];
  float s = 0.f, s2 = 0.f;
#pragma unroll
  for (int i = 0; i < 3; ++i) {
    float f = xr[t + i * 256];
    v[i] = f;
    s += f;
    s2 += f * f;
  }
#pragma unroll
  for (int off = 1; off < 64; off <<= 1) {
    s  += __shfl_xor(s, off);
    s2 += __shfl_xor(s2, off);
  }
  __shared__ float red[2][4];
  const int wave = t >> 6, lane = t & 63;
  if (lane == 0) { red[0][wave] = s; red[1][wave] = s2; }
  __syncthreads();
  s  = red[0][0] + red[0][1] + red[0][2] + red[0][3];
  s2 = red[1][0] + red[1][1] + red[1][2] + red[1][3];
  const float mu = s * (1.f / DD);
  const float var = s2 * (1.f / DD) - mu * mu;
  const float inv = rsqrtf(var + 1e-6f);
  bf16* yr = y + (size_t)row * DD;
#pragma unroll
  for (int i = 0; i < 3; ++i) {
    int c = t + i * 256;
    yr[c] = __float2bfloat16((v[i] - mu) * inv * g[c] + b[c]);
  }
}

// ---------------------------------------------------------------------------
// GEMM v5: C[M,N] = A[M,K] @ W[N,K]^T, bf16 in, f32 accum.
// Template TF = tile frags per side: TF=16 -> 256x256 tile, TF=8 -> 128x128.
// 8 waves (2M x 4N). K consumed in 32-deep slabs through a 2-slot LDS ring.
//
// LDS is stored in MFMA-FRAGMENT ORDER: each 16x32 fragment is a contiguous
// 1KB block laid out [kchunk(4)][row(16)][8 bf16]; lane l reads its operand
// at frag_base + 16*l -> dense 1024B ds_read_b128, conflict-free by
// construction (identical pattern to the global_load_lds writes). The
// fragment permutation is applied to the per-lane GLOBAL source address.
//
// Per slab: {STAGE_A(s+1); vmcnt(ACA); s_barrier; read B frags; STAGE_B(s+1);
// setprio(1); [read A frag; 4*NF MFMA] x MF; setprio(0); s_barrier}.
// Counted vmcnt: never drained to 0 in the main loop (only on the tail).
// RAW: slab s's ACA+ACB loads are the oldest; vmcnt(ACA) retires them before
// the barrier, so after the barrier every wave sees slab s in LDS.
// WAR: slot nxt was last read in iter s-1; those reads retired (lgkmcnt
// inserted by compiler before the consuming MFMA) before iter s-1's closing
// barrier.
//
// EPI 0: C=bf16. EPI 1: C=fp32 +bias+res (float4). EPI 2: C=bf16 +bias+gelu.
// ---------------------------------------------------------------------------
template <int EPI, int TF>
__global__ __launch_bounds__(512, (TF == 16) ? 4 : 6)
void gemm_kernel(const bf16* __restrict__ A, const bf16* __restrict__ W,
                 const float* __restrict__ bias, const float* __restrict__ res,
                 void* __restrict__ Cv, int N, int K)
{
  constexpr int BM   = TF * 16;       // tile side
  constexpr int MF   = TF / 2;        // per-wave m frags (wm splits in 2)
  constexpr int NF   = TF / 4;        // per-wave n frags (wn splits in 4)
  constexpr int ACA  = TF / 8;        // A stage copies per wave per slab
  constexpr int ACB  = TF / 8;        // B stage copies per wave per slab
  constexpr int ASZ  = TF * 512;      // A region shorts per slot
  constexpr int SLT  = 2 * ASZ;       // slot shorts (A + B)

  __shared__ __align__(16) short smem[2 * SLT];

  const int tid  = threadIdx.x;
  const int lane = tid & 63;
  const int w    = tid >> 6;          // wave 0..7
  const int wm   = w >> 2;            // 0..1
  const int wn   = w & 3;             // 0..3
  const int row16 = lane & 15, quad = lane >> 4;

  // panel-swizzled rasterization for L2 reuse of W
  const int gx = gridDim.x, gy = gridDim.y;
  const int lin = blockIdx.y * gx + blockIdx.x;
  const int PP  = (gy & 7) ? gy : 8;
  const int per = gx * PP;
  const int pan = lin / per, rem = lin % per;
  const int bm = (pan * PP + rem % PP) * BM;
  const int bn = (rem / PP) * BM;

  // ---- staging source (fragment-order permutation on the global address) ----
  const int rl = lane & 15;           // row within fragment
  const int kl = lane >> 4;           // k-chunk within fragment
  const bf16* Asrc = A + (size_t)(bm + w * (16 * ACA) + rl) * K + kl * 8;
  const bf16* Bsrc = W + (size_t)(bn + w * (16 * ACB) + rl) * K + kl * 8;

  const int NS = K >> 5;              // K/32 slabs

  auto STAGE_A = [&](int slot, int ko) {
    short* d = smem + slot * SLT + w * (ACA * 512);
#pragma unroll
    for (int c = 0; c < ACA; ++c)
      async_copy16(Asrc + (size_t)c * 16 * K + ko, d + c * 512);
  };
  auto STAGE_B = [&](int slot, int ko) {
    short* d = smem + slot * SLT + ASZ + w * (ACB * 512);
#pragma unroll
    for (int c = 0; c < ACB; ++c)
      async_copy16(Bsrc + (size_t)c * 16 * K + ko, d + c * 512);
  };

  // prologue: slab 0 into slot 0
  STAGE_A(0, 0);
  STAGE_B(0, 0);

  floatx4 acc[MF][NF] = {};

  for (int s = 0; s < NS; ++s) {
    const int cur = s & 1, nxt = cur ^ 1;
    const short* slot = smem + cur * SLT;
    const bool pf = (s + 1 < NS);

    if (pf) {
      STAGE_A(nxt, (s + 1) * 32);
      if constexpr (ACA == 2)
        asm volatile("s_waitcnt vmcnt(2)" ::: "memory");
      else
        asm volatile("s_waitcnt vmcnt(1)" ::: "memory");
    } else {
      asm volatile("s_waitcnt vmcnt(0)" ::: "memory");
    }
    __builtin_amdgcn_s_barrier();   // slab s visible to all waves

    short8 bfr[NF];
#pragma unroll
    for (int nt = 0; nt < NF; ++nt)
      bfr[nt] = *(const short8*)&slot[ASZ + (wn * NF + nt) * 512 + lane * 8];

    if (pf) STAGE_B(nxt, (s + 1) * 32);

    __builtin_amdgcn_s_setprio(1);
#pragma unroll
    for (int mt = 0; mt < MF; ++mt) {
      const short8 af = *(const short8*)&slot[(wm * MF + mt) * 512 + lane * 8];
#pragma unroll
      for (int nt = 0; nt < NF; ++nt)
        acc[mt][nt] = mfma_bf16(bfr[nt], af, acc[mt][nt]);   // C^T trick
    }
    __builtin_amdgcn_s_setprio(0);
    __builtin_amdgcn_s_barrier();   // protect slot cur before it is restaged
  }

  // ---------------- epilogue ----------------
  floatx4 bias4[NF] = {};
  if (EPI != 0) {
#pragma unroll
    for (int nt = 0; nt < NF; ++nt)
      bias4[nt] = *(const floatx4*)&bias[bn + wn * (NF * 16) + nt * 16 + quad * 4];
  }

#pragma unroll
  for (int mt = 0; mt < MF; ++mt) {
    const int row = bm + wm * (MF * 16) + mt * 16 + row16;
    if (EPI == 1) {
      const float* rr = res + (size_t)row * N;
      float* cr = (float*)Cv + (size_t)row * N;
#pragma unroll
      for (int nt = 0; nt < NF; ++nt) {
        const int col = bn + wn * (NF * 16) + nt * 16 + quad * 4;
        const floatx4 rv = *(const floatx4*)&rr[col];
        floatx4 o;
#pragma unroll
        for (int r = 0; r < 4; ++r) o[r] = acc[mt][nt][r] + bias4[nt][r] + rv[r];
        *(floatx4*)&cr[col] = o;
      }
    } else {
      bf16* cr = (bf16*)Cv + (size_t)row * N;
#pragma unroll
      for (int nt = 0; nt < NF; ++nt) {
        const int col = bn + wn * (NF * 16) + nt * 16 + quad * 4;
        shortx4 pk;
#pragma unroll
        for (int r = 0; r < 4; ++r) {
          float v = acc[mt][nt][r] + bias4[nt][r];
          if (EPI == 2) v = gelu_f(v);
          pk[r] = bf16_bits(v);
        }
        *(shortx4*)&cr[col] = pk;
      }
    }
  }
}

// ---------------------------------------------------------------------------
// V transpose: qkv [nb,N,3,H,64] -> Vt [nb*H, 64, N]
// ---------------------------------------------------------------------------
__global__ __launch_bounds__(256)
void vtrans_kernel(const bf16* __restrict__ qkv, bf16* __restrict__ vt)
{
  const int bh = blockIdx.y;
  const int b = bh / HH, h = bh % HH;
  const int n0 = blockIdx.x * 64;
  __shared__ __align__(16) short tile[64 * 72];
  const int tid = threadIdx.x;

  const int r = tid >> 2, c16 = (tid & 3) * 16;
  const bf16* src = qkv + (size_t)(b * NN + n0 + r) * 2304 + 2 * DD + h * 64 + c16;
  *(short8*)&tile[r * 72 + c16]     = *(const short8*)(src);
  *(short8*)&tile[r * 72 + c16 + 8] = *(const short8*)(src + 8);
  __syncthreads();

#pragma unroll
  for (int it = 0; it < 2; ++it) {
    const int d  = (tid >> 3) + it * 32;
    const int jg = (tid & 7) * 8;
    short8 o;
#pragma unroll
    for (int t = 0; t < 8; ++t) ((short*)&o)[t] = tile[(jg + t) * 72 + d];
    *(short8*)&vt[((size_t)bh * 64 + d) * NN + n0 + jg] = o;
  }
}

// ---------------------------------------------------------------------------
// Flash attention v3 (fixed-offset softmax, ones-MFMA row sums, S^T P-writes).
// Block = (b,h) x 128 Q rows; wave owns 32 rows.
// ---------------------------------------------------------------------------
__global__ __launch_bounds__(256, 2)
void attn_kernel(const bf16* __restrict__ qkv, const bf16* __restrict__ vt,
                 bf16* __restrict__ out)
{
  const int bh = blockIdx.y;
  const int b = bh / HH, h = bh % HH;
  const int q0 = blockIdx.x * 128;
  const int tid = threadIdx.x;
  const int lane = tid & 63;
  const int wave = tid >> 6;
  const int row16 = lane & 15, quad = lane >> 4;

  __shared__ __align__(16) short sK[64 * 72];     // [j][d]
  __shared__ __align__(16) short sVt[64 * 72];    // [d][j]
  __shared__ __align__(16) short sP[4][32 * 72];  // per-wave P [q][j]

  const bf16* base  = qkv + (size_t)b * NN * 2304 + h * 64;
  const bf16* vbase = vt + (size_t)bh * 64 * NN;

  short8 qf[2][2];
#pragma unroll
  for (int qg = 0; qg < 2; ++qg) {
    const bf16* qrow = base + (size_t)(q0 + wave * 32 + qg * 16 + row16) * 2304;
    qf[qg][0] = *(const short8*)(qrow + quad * 8);
    qf[qg][1] = *(const short8*)(qrow + 32 + quad * 8);
  }

  floatx4 o_acc[2][4] = {};
  floatx4 l_acc[2] = {};
  const short8 ones = { (short)0x3F80, (short)0x3F80, (short)0x3F80, (short)0x3F80,
                        (short)0x3F80, (short)0x3F80, (short)0x3F80, (short)0x3F80 };

  const int sr = tid >> 2;
  const int sc = (tid & 3) * 16;
  const float ESC = 0.1803368801f;   // log2(e)/8

  for (int jt = 0; jt < NN / 64; ++jt) {
    const int j0 = jt * 64;
    {
      const bf16* kp = base + (size_t)(j0 + sr) * 2304 + DD + sc;
      *(short8*)&sK[sr * 72 + sc]     = *(const short8*)(kp);
      *(short8*)&sK[sr * 72 + sc + 8] = *(const short8*)(kp + 8);
      const bf16* vp = vbase + (size_t)sr * NN + j0 + sc;
      *(short8*)&sVt[sr * 72 + sc]     = *(const short8*)(vp);
      *(short8*)&sVt[sr * 72 + sc + 8] = *(const short8*)(vp + 8);
    }
    __syncthreads();

#pragma unroll
    for (int nt = 0; nt < 4; ++nt) {
      short8 kb0 = *(const short8*)&sK[(nt * 16 + row16) * 72 + quad * 8];
      short8 kb1 = *(const short8*)&sK[(nt * 16 + row16) * 72 + 32 + quad * 8];
#pragma unroll
      for (int qg = 0; qg < 2; ++qg) {
        floatx4 st = {};
        st = mfma_bf16(kb0, qf[qg][0], st);
        st = mfma_bf16(kb1, qf[qg][1], st);
        shortx4 pk;
#pragma unroll
        for (int r = 0; r < 4; ++r)
          pk[r] = bf16_bits(exp2f(fminf(st[r] * ESC, 30.f)));
        *(shortx4*)&sP[wave][(qg * 16 + row16) * 72 + nt * 16 + quad * 4] = pk;
      }
    }

    short8 vb[4][2];
#pragma unroll
    for (int dt = 0; dt < 4; ++dt) {
      vb[dt][0] = *(const short8*)&sVt[(dt * 16 + row16) * 72 + quad * 8];
      vb[dt][1] = *(const short8*)&sVt[(dt * 16 + row16) * 72 + 32 + quad * 8];
    }
#pragma unroll
    for (int qg = 0; qg < 2; ++qg) {
      short8 pf0 = *(const short8*)&sP[wave][(qg * 16 + row16) * 72 + quad * 8];
      short8 pf1 = *(const short8*)&sP[wave][(qg * 16 + row16) * 72 + 32 + quad * 8];
      l_acc[qg] = mfma_bf16(pf0, ones, l_acc[qg]);
      l_acc[qg] = mfma_bf16(pf1, ones, l_acc[qg]);
#pragma unroll
      for (int dt = 0; dt < 4; ++dt) {
        o_acc[qg][dt] = mfma_bf16(pf0, vb[dt][0], o_acc[qg][dt]);
        o_acc[qg][dt] = mfma_bf16(pf1, vb[dt][1], o_acc[qg][dt]);
      }
    }
    __syncthreads();
  }

#pragma unroll
  for (int qg = 0; qg < 2; ++qg) {
#pragma unroll
    for (int r = 0; r < 4; ++r) {
      const float inv = 1.f / l_acc[qg][r];
      const size_t n = (size_t)(b * NN + q0 + wave * 32 + qg * 16 + quad * 4 + r);
#pragma unroll
      for (int dt = 0; dt < 4; ++dt) {
        out[n * DD + h * 64 + dt * 16 + row16] =
            __float2bfloat16(o_acc[qg][dt][r] * inv);
      }
    }
  }
}

// ---------------------------------------------------------------------------
extern "C" void kernel_launch(void* const* d_in, const int* in_sizes, int n_in,
                              void* d_out, int out_size, void* d_ws, size_t ws_size,
                              hipStream_t stream)
{
  const float* x       = (const float*)d_in[0];
  const float* qkv_w   = (const float*)d_in[1];
  const float* proj_w  = (const float*)d_in[2];
  const float* proj_b  = (const float*)d_in[3];
  const float* fc1_w   = (const float*)d_in[4];
  const float* fc1_b   = (const float*)d_in[5];
  const float* fc2_w   = (const float*)d_in[6];
  const float* fc2_b   = (const float*)d_in[7];
  const float* norm1_g = (const float*)d_in[8];
  const float* norm1_b = (const float*)d_in[9];
  const float* norm2_g = (const float*)d_in[10];
  const float* norm2_b = (const float*)d_in[11];
  float* out = (float*)d_out;

  const int M = BB * NN;  // 16384 rows
  char* ws = (char*)d_ws;

  bf16* wq = (bf16*)ws;                                  // [2304,768]
  bf16* wp = wq + (size_t)3 * DD * DD;                   // [768,768]
  bf16* w1 = wp + (size_t)DD * DD;                       // [3072,768]
  bf16* w2 = w1 + (size_t)HID * DD;                      // [768,3072]
  bf16* xn = w2 + (size_t)DD * HID;                      // [M,768] bf16
  char* p2 = (char*)(xn + (size_t)M * DD);
  const size_t base_b = (size_t)(p2 - ws);               // 39,321,600

  int NBc = 1;
  for (int c = 16; c >= 1; c >>= 1)
    if (ws_size >= base_b + (size_t)c * 1024 * 7680) { NBc = c; break; }

  const int Rc = NBc * NN;
  bf16* qkvb = (bf16*)p2;                        // [Rc, 2304]
  bf16* aob  = qkvb + (size_t)Rc * 2304;         // [Rc, 768]
  bf16* vtb  = aob  + (size_t)Rc * DD;           // [NBc*H, 64, N]
  bf16* hb   = (bf16*)p2;                        // [Rc, 3072] (MLP phase)

  cvt_kernel<<<(3 * DD * DD / 4 + 255) / 256, 256, 0, stream>>>(qkv_w, wq, 3 * DD * DD / 4);
  cvt_kernel<<<(DD * DD / 4 + 255) / 256, 256, 0, stream>>>(proj_w, wp, DD * DD / 4);
  cvt_kernel<<<(HID * DD / 4 + 255) / 256, 256, 0, stream>>>(fc1_w, w1, HID * DD / 4);
  cvt_kernel<<<(DD * HID / 4 + 255) / 256, 256, 0, stream>>>(fc2_w, w2, DD * HID / 4);

  ln_kernel<<<M, 256, 0, stream>>>(x, norm1_g, norm1_b, xn);

  for (int c = 0; c < BB / NBc; ++c) {
    const size_t r0 = (size_t)c * Rc;
    gemm_kernel<0, 16><<<dim3(3 * DD / 256, Rc / 256), 512, 0, stream>>>(
        xn + r0 * DD, wq, nullptr, nullptr, qkvb, 3 * DD, DD);
    vtrans_kernel<<<dim3(NN / 64, NBc * HH), 256, 0, stream>>>(qkvb, vtb);
    attn_kernel<<<dim3(NN / 128, NBc * HH), 256, 0, stream>>>(qkvb, vtb, aob);
    gemm_kernel<1, 8><<<dim3(DD / 128, Rc / 128), 512, 0, stream>>>(
        aob, wp, proj_b, x + r0 * DD, out + r0 * DD, DD, DD);
  }

  ln_kernel<<<M, 256, 0, stream>>>(out, norm2_g, norm2_b, xn);

  for (int c = 0; c < BB / NBc; ++c) {
    const size_t r0 = (size_t)c * Rc;
    gemm_kernel<2, 16><<<dim3(HID / 256, Rc / 256), 512, 0, stream>>>(
        xn + r0 * DD, w1, fc1_b, nullptr, hb, HID, DD);
    gemm_kernel<1, 8><<<dim3(DD / 128, Rc / 128), 512, 0, stream>>>(
        hb, w2, fc2_b, out + r0 * DD, out + r0 * DD, DD, HID);
  }
}

// Round 3
// 639.652 us; speedup vs baseline: 2.4895x; 2.4895x over previous
//
#include <hip/hip_runtime.h>
#include <hip/hip_bf16.h>
#include <math.h>

using bf16 = __hip_bfloat16;
typedef __attribute__((ext_vector_type(8))) short short8;
typedef __attribute__((ext_vector_type(4))) short shortx4;
typedef __attribute__((ext_vector_type(4))) float floatx4;

// Problem constants
#define BB 16
#define NN 1024
#define DD 768
#define HH 12
#define HD 64
#define HID 3072

__device__ __forceinline__ floatx4 mfma_bf16(short8 a, short8 b, floatx4 c) {
  return __builtin_amdgcn_mfma_f32_16x16x32_bf16(a, b, c, 0, 0, 0);
}

__device__ __forceinline__ short bf16_bits(float f) {
  union { bf16 h; short s; } u;
  u.h = __float2bfloat16(f);
  return u.s;
}

__device__ __forceinline__ void async_copy16(const void* g, void* l) {
  __builtin_amdgcn_global_load_lds(
      (const __attribute__((address_space(1))) unsigned int*)g,
      (__attribute__((address_space(3))) unsigned int*)l,
      16, 0, 0);
}

// tanh-form gelu via exp2 (verified absmax-equal in prior rounds)
__device__ __forceinline__ float gelu_f(float x) {
  const float z = x * fmaf(0.10294324f, x * x, 2.3022082f);
  const float e = exp2f(z);
  return x - x * __builtin_amdgcn_rcpf(e + 1.0f);
}

// ---------------------------------------------------------------------------
// fp32 -> bf16 conversion (weights), 4 elements/thread.
// ---------------------------------------------------------------------------
__global__ __launch_bounds__(256)
void cvt_kernel(const float* __restrict__ in, bf16* __restrict__ out, int n4)
{
  const int i = blockIdx.x * 256 + threadIdx.x;
  if (i >= n4) return;
  const float4 v = ((const float4*)in)[i];
  shortx4 o;
  o.x = bf16_bits(v.x); o.y = bf16_bits(v.y);
  o.z = bf16_bits(v.z); o.w = bf16_bits(v.w);
  ((shortx4*)out)[i] = o;
}

// ---------------------------------------------------------------------------
// LayerNorm: fp32 in, bf16 out. One block (256 thr) per row of 768.
// ---------------------------------------------------------------------------
__global__ __launch_bounds__(256)
void ln_kernel(const float* __restrict__ x, const float* __restrict__ g,
               const float* __restrict__ b, bf16* __restrict__ y)
{
  const int row = blockIdx.x;
  const int t = threadIdx.x;
  const float* xr = x + (size_t)row * DD;
  float v[3];
  float s = 0.f, s2 = 0.f;
#pragma unroll
  for (int i = 0; i < 3; ++i) {
    float f = xr[t + i * 256];
    v[i] = f;
    s += f;
    s2 += f * f;
  }
#pragma unroll
  for (int off = 1; off < 64; off <<= 1) {
    s  += __shfl_xor(s, off);
    s2 += __shfl_xor(s2, off);
  }
  __shared__ float red[2][4];
  const int wave = t >> 6, lane = t & 63;
  if (lane == 0) { red[0][wave] = s; red[1][wave] = s2; }
  __syncthreads();
  s  = red[0][0] + red[0][1] + red[0][2] + red[0][3];
  s2 = red[1][0] + red[1][1] + red[1][2] + red[1][3];
  const float mu = s * (1.f / DD);
  const float var = s2 * (1.f / DD) - mu * mu;
  const float inv = rsqrtf(var + 1e-6f);
  bf16* yr = y + (size_t)row * DD;
#pragma unroll
  for (int i = 0; i < 3; ++i) {
    int c = t + i * 256;
    yr[c] = __float2bfloat16((v[i] - mu) * inv * g[c] + b[c]);
  }
}

// ---------------------------------------------------------------------------
// GEMM v6: C[M,N] = A[M,K] @ W[N,K]^T, bf16 in, f32 accum.
// Geometry template: BM (tile side), WVM x WVN wave grid.
//   <256,2,4>: 8 waves, wave tile 128x64, LB(512,2)  -> 1 block/CU, 3-slot
//              LDS ring (96 KB), prefetch distance 2, steady vmcnt(6).
//   <128,2,2>: 4 waves, wave tile 64x64,  LB(256,4)  -> 4 blocks/CU, 2-slot
//              ring (32 KB), prefetch distance 1, steady vmcnt(2).
//
// LDS in MFMA-FRAGMENT ORDER (proven conflict-free in r2: SQ_LDS_BANK_CONFLICT
// = 0): each 16x32 fragment is a contiguous 1KB block; lane l reads operand at
// frag_base + 16*l (dense ds_read_b128, same pattern as the staging writes).
// Fragment permutation applied to the per-lane GLOBAL source of
// global_load_lds.
//
// Counted vmcnt (never 0 mid-loop). RAW: vmcnt(N) retires all loads older
// than the in-flight prefetches -> slab s fully in LDS before the barrier.
// WAR: the slot being restaged was last ds_read one iteration ago; those
// reads retired (compiler lgkmcnt before consuming MFMA) before that
// iteration's closing barrier.
//
// EPI 0: C=bf16. EPI 1: C=fp32 +bias+res (float4). EPI 2: C=bf16 +bias+gelu.
// ---------------------------------------------------------------------------
template <int EPI, int BM, int WVM, int WVN>
__global__ __launch_bounds__(WVM * WVN * 64, (BM == 256) ? 2 : 4)
void gemm_kernel(const bf16* __restrict__ A, const bf16* __restrict__ W,
                 const float* __restrict__ bias, const float* __restrict__ res,
                 void* __restrict__ Cv, int N, int K)
{
  constexpr int NWV  = WVM * WVN;      // waves per block
  constexpr int MF   = BM / (16 * WVM);
  constexpr int NF   = BM / (16 * WVN);
  constexpr int FR   = BM / 16;        // fragments per side per slab
  constexpr int AC   = FR / NWV;       // stage copies per wave per side (=2)
  constexpr int ASZ  = FR * 512;       // A region shorts per slot
  constexpr int SLT  = 2 * ASZ;        // slot shorts (A + B)
  constexpr int NSL  = (BM == 256) ? 3 : 2;

  __shared__ __align__(16) short smem[NSL * SLT];

  const int tid  = threadIdx.x;
  const int lane = tid & 63;
  const int w    = tid >> 6;
  const int wn   = w % WVN;
  const int wm   = w / WVN;
  const int row16 = lane & 15, quad = lane >> 4;

  // panel-swizzled rasterization for L2 reuse of W
  const int gx = gridDim.x, gy = gridDim.y;
  const int lin = blockIdx.y * gx + blockIdx.x;
  const int PP  = (gy & 7) ? gy : 8;
  const int per = gx * PP;
  const int pan = lin / per, rem = lin % per;
  const int bm = (pan * PP + rem % PP) * BM;
  const int bn = (rem / PP) * BM;

  // staging source (fragment-order permutation on the global address)
  const int rl = lane & 15;            // row within fragment
  const int kl = lane >> 4;            // k-chunk within fragment
  const bf16* Asrc = A + (size_t)(bm + w * (16 * AC) + rl) * K + kl * 8;
  const bf16* Bsrc = W + (size_t)(bn + w * (16 * AC) + rl) * K + kl * 8;

  const int NS = K >> 5;               // K/32 slabs

  auto STAGE_A = [&](int slot, int ko) {
    short* d = smem + slot * SLT + w * (AC * 512);
#pragma unroll
    for (int c = 0; c < AC; ++c)
      async_copy16(Asrc + (size_t)c * 16 * K + ko, d + c * 512);
  };
  auto STAGE_B = [&](int slot, int ko) {
    short* d = smem + slot * SLT + ASZ + w * (AC * 512);
#pragma unroll
    for (int c = 0; c < AC; ++c)
      async_copy16(Bsrc + (size_t)c * 16 * K + ko, d + c * 512);
  };

  // prologue: stage slabs 0..NSL-2
#pragma unroll
  for (int u = 0; u < NSL - 1; ++u) {
    STAGE_A(u, u * 32);
    STAGE_B(u, u * 32);
  }

  floatx4 acc[MF][NF] = {};

  for (int s = 0; s < NS; ++s) {
    const int cur = s % NSL;
    const short* slot = smem + cur * SLT;
    const int p = s + NSL - 1;         // slab to prefetch this iteration

    if (p < NS) {
      STAGE_A(p % NSL, p * 32);
      if constexpr (NSL == 3)
        asm volatile("s_waitcnt vmcnt(6)" ::: "memory");  // A(s+1),B(s+1),A(s+2) in flight
      else
        asm volatile("s_waitcnt vmcnt(2)" ::: "memory");  // A(s+1) in flight
    } else if (NSL == 3 && p == NS) {
      asm volatile("s_waitcnt vmcnt(4)" ::: "memory");    // A,B(NS-1) in flight
    } else {
      asm volatile("s_waitcnt vmcnt(0)" ::: "memory");
    }
    __builtin_amdgcn_s_barrier();      // slab s visible to all waves

    short8 bfr[NF];
#pragma unroll
    for (int nt = 0; nt < NF; ++nt)
      bfr[nt] = *(const short8*)&slot[ASZ + (wn * NF + nt) * 512 + lane * 8];

    if (p < NS) STAGE_B(p % NSL, p * 32);

    __builtin_amdgcn_s_setprio(1);
#pragma unroll
    for (int mt = 0; mt < MF; ++mt) {
      const short8 af = *(const short8*)&slot[(wm * MF + mt) * 512 + lane * 8];
#pragma unroll
      for (int nt = 0; nt < NF; ++nt)
        acc[mt][nt] = mfma_bf16(bfr[nt], af, acc[mt][nt]);   // C^T trick
    }
    __builtin_amdgcn_s_setprio(0);
    __builtin_amdgcn_s_barrier();      // protect slot cur before restage
  }

  // ---------------- epilogue ----------------
  floatx4 bias4[NF] = {};
  if (EPI != 0) {
#pragma unroll
    for (int nt = 0; nt < NF; ++nt)
      bias4[nt] = *(const floatx4*)&bias[bn + wn * (NF * 16) + nt * 16 + quad * 4];
  }

#pragma unroll
  for (int mt = 0; mt < MF; ++mt) {
    const int row = bm + wm * (MF * 16) + mt * 16 + row16;
    if (EPI == 1) {
      const float* rr = res + (size_t)row * N;
      float* cr = (float*)Cv + (size_t)row * N;
#pragma unroll
      for (int nt = 0; nt < NF; ++nt) {
        const int col = bn + wn * (NF * 16) + nt * 16 + quad * 4;
        const floatx4 rv = *(const floatx4*)&rr[col];
        floatx4 o;
#pragma unroll
        for (int r = 0; r < 4; ++r) o[r] = acc[mt][nt][r] + bias4[nt][r] + rv[r];
        *(floatx4*)&cr[col] = o;
      }
    } else {
      bf16* cr = (bf16*)Cv + (size_t)row * N;
#pragma unroll
      for (int nt = 0; nt < NF; ++nt) {
        const int col = bn + wn * (NF * 16) + nt * 16 + quad * 4;
        shortx4 pk;
#pragma unroll
        for (int r = 0; r < 4; ++r) {
          float v = acc[mt][nt][r] + bias4[nt][r];
          if (EPI == 2) v = gelu_f(v);
          pk[r] = bf16_bits(v);
        }
        *(shortx4*)&cr[col] = pk;
      }
    }
  }
}

// ---------------------------------------------------------------------------
// V transpose: qkv [nb,N,3,H,64] -> Vt [nb*H, 64, N]
// ---------------------------------------------------------------------------
__global__ __launch_bounds__(256)
void vtrans_kernel(const bf16* __restrict__ qkv, bf16* __restrict__ vt)
{
  const int bh = blockIdx.y;
  const int b = bh / HH, h = bh % HH;
  const int n0 = blockIdx.x * 64;
  __shared__ __align__(16) short tile[64 * 72];
  const int tid = threadIdx.x;

  const int r = tid >> 2, c16 = (tid & 3) * 16;
  const bf16* src = qkv + (size_t)(b * NN + n0 + r) * 2304 + 2 * DD + h * 64 + c16;
  *(short8*)&tile[r * 72 + c16]     = *(const short8*)(src);
  *(short8*)&tile[r * 72 + c16 + 8] = *(const short8*)(src + 8);
  __syncthreads();

#pragma unroll
  for (int it = 0; it < 2; ++it) {
    const int d  = (tid >> 3) + it * 32;
    const int jg = (tid & 7) * 8;
    short8 o;
#pragma unroll
    for (int t = 0; t < 8; ++t) ((short*)&o)[t] = tile[(jg + t) * 72 + d];
    *(short8*)&vt[((size_t)bh * 64 + d) * NN + n0 + jg] = o;
  }
}

// ---------------------------------------------------------------------------
// Flash attention v3 (fixed-offset softmax, ones-MFMA row sums, S^T P-writes).
// Block = (b,h) x 128 Q rows; wave owns 32 rows.
// ---------------------------------------------------------------------------
__global__ __launch_bounds__(256, 2)
void attn_kernel(const bf16* __restrict__ qkv, const bf16* __restrict__ vt,
                 bf16* __restrict__ out)
{
  const int bh = blockIdx.y;
  const int b = bh / HH, h = bh % HH;
  const int q0 = blockIdx.x * 128;
  const int tid = threadIdx.x;
  const int lane = tid & 63;
  const int wave = tid >> 6;
  const int row16 = lane & 15, quad = lane >> 4;

  __shared__ __align__(16) short sK[64 * 72];     // [j][d]
  __shared__ __align__(16) short sVt[64 * 72];    // [d][j]
  __shared__ __align__(16) short sP[4][32 * 72];  // per-wave P [q][j]

  const bf16* base  = qkv + (size_t)b * NN * 2304 + h * 64;
  const bf16* vbase = vt + (size_t)bh * 64 * NN;

  short8 qf[2][2];
#pragma unroll
  for (int qg = 0; qg < 2; ++qg) {
    const bf16* qrow = base + (size_t)(q0 + wave * 32 + qg * 16 + row16) * 2304;
    qf[qg][0] = *(const short8*)(qrow + quad * 8);
    qf[qg][1] = *(const short8*)(qrow + 32 + quad * 8);
  }

  floatx4 o_acc[2][4] = {};
  floatx4 l_acc[2] = {};
  const short8 ones = { (short)0x3F80, (short)0x3F80, (short)0x3F80, (short)0x3F80,
                        (short)0x3F80, (short)0x3F80, (short)0x3F80, (short)0x3F80 };

  const int sr = tid >> 2;
  const int sc = (tid & 3) * 16;
  const float ESC = 0.1803368801f;   // log2(e)/8

  for (int jt = 0; jt < NN / 64; ++jt) {
    const int j0 = jt * 64;
    {
      const bf16* kp = base + (size_t)(j0 + sr) * 2304 + DD + sc;
      *(short8*)&sK[sr * 72 + sc]     = *(const short8*)(kp);
      *(short8*)&sK[sr * 72 + sc + 8] = *(const short8*)(kp + 8);
      const bf16* vp = vbase + (size_t)sr * NN + j0 + sc;
      *(short8*)&sVt[sr * 72 + sc]     = *(const short8*)(vp);
      *(short8*)&sVt[sr * 72 + sc + 8] = *(const short8*)(vp + 8);
    }
    __syncthreads();

#pragma unroll
    for (int nt = 0; nt < 4; ++nt) {
      short8 kb0 = *(const short8*)&sK[(nt * 16 + row16) * 72 + quad * 8];
      short8 kb1 = *(const short8*)&sK[(nt * 16 + row16) * 72 + 32 + quad * 8];
#pragma unroll
      for (int qg = 0; qg < 2; ++qg) {
        floatx4 st = {};
        st = mfma_bf16(kb0, qf[qg][0], st);
        st = mfma_bf16(kb1, qf[qg][1], st);
        shortx4 pk;
#pragma unroll
        for (int r = 0; r < 4; ++r)
          pk[r] = bf16_bits(exp2f(fminf(st[r] * ESC, 30.f)));
        *(shortx4*)&sP[wave][(qg * 16 + row16) * 72 + nt * 16 + quad * 4] = pk;
      }
    }

    short8 vb[4][2];
#pragma unroll
    for (int dt = 0; dt < 4; ++dt) {
      vb[dt][0] = *(const short8*)&sVt[(dt * 16 + row16) * 72 + quad * 8];
      vb[dt][1] = *(const short8*)&sVt[(dt * 16 + row16) * 72 + 32 + quad * 8];
    }
#pragma unroll
    for (int qg = 0; qg < 2; ++qg) {
      short8 pf0 = *(const short8*)&sP[wave][(qg * 16 + row16) * 72 + quad * 8];
      short8 pf1 = *(const short8*)&sP[wave][(qg * 16 + row16) * 72 + 32 + quad * 8];
      l_acc[qg] = mfma_bf16(pf0, ones, l_acc[qg]);
      l_acc[qg] = mfma_bf16(pf1, ones, l_acc[qg]);
#pragma unroll
      for (int dt = 0; dt < 4; ++dt) {
        o_acc[qg][dt] = mfma_bf16(pf0, vb[dt][0], o_acc[qg][dt]);
        o_acc[qg][dt] = mfma_bf16(pf1, vb[dt][1], o_acc[qg][dt]);
      }
    }
    __syncthreads();
  }

#pragma unroll
  for (int qg = 0; qg < 2; ++qg) {
#pragma unroll
    for (int r = 0; r < 4; ++r) {
      const float inv = 1.f / l_acc[qg][r];
      const size_t n = (size_t)(b * NN + q0 + wave * 32 + qg * 16 + quad * 4 + r);
#pragma unroll
      for (int dt = 0; dt < 4; ++dt) {
        out[n * DD + h * 64 + dt * 16 + row16] =
            __float2bfloat16(o_acc[qg][dt][r] * inv);
      }
    }
  }
}

// ---------------------------------------------------------------------------
extern "C" void kernel_launch(void* const* d_in, const int* in_sizes, int n_in,
                              void* d_out, int out_size, void* d_ws, size_t ws_size,
                              hipStream_t stream)
{
  const float* x       = (const float*)d_in[0];
  const float* qkv_w   = (const float*)d_in[1];
  const float* proj_w  = (const float*)d_in[2];
  const float* proj_b  = (const float*)d_in[3];
  const float* fc1_w   = (const float*)d_in[4];
  const float* fc1_b   = (const float*)d_in[5];
  const float* fc2_w   = (const float*)d_in[6];
  const float* fc2_b   = (const float*)d_in[7];
  const float* norm1_g = (const float*)d_in[8];
  const float* norm1_b = (const float*)d_in[9];
  const float* norm2_g = (const float*)d_in[10];
  const float* norm2_b = (const float*)d_in[11];
  float* out = (float*)d_out;

  const int M = BB * NN;  // 16384 rows
  char* ws = (char*)d_ws;

  bf16* wq = (bf16*)ws;                                  // [2304,768]
  bf16* wp = wq + (size_t)3 * DD * DD;                   // [768,768]
  bf16* w1 = wp + (size_t)DD * DD;                       // [3072,768]
  bf16* w2 = w1 + (size_t)HID * DD;                      // [768,3072]
  bf16* xn = w2 + (size_t)DD * HID;                      // [M,768] bf16
  char* p2 = (char*)(xn + (size_t)M * DD);
  const size_t base_b = (size_t)(p2 - ws);               // 39,321,600

  int NBc = 1;
  for (int c = 16; c >= 1; c >>= 1)
    if (ws_size >= base_b + (size_t)c * 1024 * 7680) { NBc = c; break; }

  const int Rc = NBc * NN;
  bf16* qkvb = (bf16*)p2;                        // [Rc, 2304]
  bf16* aob  = qkvb + (size_t)Rc * 2304;         // [Rc, 768]
  bf16* vtb  = aob  + (size_t)Rc * DD;           // [NBc*H, 64, N]
  bf16* hb   = (bf16*)p2;                        // [Rc, 3072] (MLP phase)

  cvt_kernel<<<(3 * DD * DD / 4 + 255) / 256, 256, 0, stream>>>(qkv_w, wq, 3 * DD * DD / 4);
  cvt_kernel<<<(DD * DD / 4 + 255) / 256, 256, 0, stream>>>(proj_w, wp, DD * DD / 4);
  cvt_kernel<<<(HID * DD / 4 + 255) / 256, 256, 0, stream>>>(fc1_w, w1, HID * DD / 4);
  cvt_kernel<<<(DD * HID / 4 + 255) / 256, 256, 0, stream>>>(fc2_w, w2, DD * HID / 4);

  ln_kernel<<<M, 256, 0, stream>>>(x, norm1_g, norm1_b, xn);

  for (int c = 0; c < BB / NBc; ++c) {
    const size_t r0 = (size_t)c * Rc;
    gemm_kernel<0, 256, 2, 4><<<dim3(3 * DD / 256, Rc / 256), 512, 0, stream>>>(
        xn + r0 * DD, wq, nullptr, nullptr, qkvb, 3 * DD, DD);
    vtrans_kernel<<<dim3(NN / 64, NBc * HH), 256, 0, stream>>>(qkvb, vtb);
    attn_kernel<<<dim3(NN / 128, NBc * HH), 256, 0, stream>>>(qkvb, vtb, aob);
    gemm_kernel<1, 128, 2, 2><<<dim3(DD / 128, Rc / 128), 256, 0, stream>>>(
        aob, wp, proj_b, x + r0 * DD, out + r0 * DD, DD, DD);
  }

  ln_kernel<<<M, 256, 0, stream>>>(out, norm2_g, norm2_b, xn);

  for (int c = 0; c < BB / NBc; ++c) {
    const size_t r0 = (size_t)c * Rc;
    gemm_kernel<2, 256, 2, 4><<<dim3(HID / 256, Rc / 256), 512, 0, stream>>>(
        xn + r0 * DD, w1, fc1_b, nullptr, hb, HID, DD);
    gemm_kernel<1, 128, 2, 2><<<dim3(DD / 128, Rc / 128), 256, 0, stream>>>(
        hb, w2, fc2_b, out + r0 * DD, out + r0 * DD, DD, HID);
  }
}

// Round 4
// 558.187 us; speedup vs baseline: 2.8528x; 1.1459x over previous
//
#include <hip/hip_runtime.h>
#include <hip/hip_bf16.h>
#include <math.h>

using bf16 = __hip_bfloat16;
typedef __attribute__((ext_vector_type(8))) short short8;
typedef __attribute__((ext_vector_type(4))) short shortx4;
typedef __attribute__((ext_vector_type(4))) float floatx4;

// Problem constants
#define BB 16
#define NN 1024
#define DD 768
#define HH 12
#define HD 64
#define HID 3072

__device__ __forceinline__ floatx4 mfma_bf16(short8 a, short8 b, floatx4 c) {
  return __builtin_amdgcn_mfma_f32_16x16x32_bf16(a, b, c, 0, 0, 0);
}

__device__ __forceinline__ short bf16_bits(float f) {
  union { bf16 h; short s; } u;
  u.h = __float2bfloat16(f);
  return u.s;
}

__device__ __forceinline__ void async_copy16(const void* g, void* l) {
  __builtin_amdgcn_global_load_lds(
      (const __attribute__((address_space(1))) unsigned int*)g,
      (__attribute__((address_space(3))) unsigned int*)l,
      16, 0, 0);
}

// tanh-form gelu via exp2. Passed with identical absmax (0.03125) in three
// prior rounds; ~8 VALU ops vs ~40 for erff -> saves ~20us of chip-wide VALU
// on the 50M-element fc1 epilogue.
__device__ __forceinline__ float gelu_f(float x) {
  const float z = x * fmaf(0.10294324f, x * x, 2.3022082f);
  const float e = exp2f(z);
  return x - x * __builtin_amdgcn_rcpf(e + 1.0f);
}

// ---------------------------------------------------------------------------
// fp32 -> bf16 conversion (weights), 4 elements/thread.
// ---------------------------------------------------------------------------
__global__ __launch_bounds__(256)
void cvt_kernel(const float* __restrict__ in, bf16* __restrict__ out, int n4)
{
  const int i = blockIdx.x * 256 + threadIdx.x;
  if (i >= n4) return;
  const float4 v = ((const float4*)in)[i];
  shortx4 o;
  o.x = bf16_bits(v.x); o.y = bf16_bits(v.y);
  o.z = bf16_bits(v.z); o.w = bf16_bits(v.w);
  ((shortx4*)out)[i] = o;
}

// ---------------------------------------------------------------------------
// LayerNorm: fp32 in, bf16 out. One block (256 thr) per row of 768.
// ---------------------------------------------------------------------------
__global__ __launch_bounds__(256)
void ln_kernel(const float* __restrict__ x, const float* __restrict__ g,
               const float* __restrict__ b, bf16* __restrict__ y)
{
  const int row = blockIdx.x;
  const int t = threadIdx.x;
  const float* xr = x + (size_t)row * DD;
  float v[3];
  float s = 0.f, s2 = 0.f;
#pragma unroll
  for (int i = 0; i < 3; ++i) {
    float f = xr[t + i * 256];
    v[i] = f;
    s += f;
    s2 += f * f;
  }
#pragma unroll
  for (int off = 1; off < 64; off <<= 1) {
    s  += __shfl_xor(s, off);
    s2 += __shfl_xor(s2, off);
  }
  __shared__ float red[2][4];
  const int wave = t >> 6, lane = t & 63;
  if (lane == 0) { red[0][wave] = s; red[1][wave] = s2; }
  __syncthreads();
  s  = red[0][0] + red[0][1] + red[0][2] + red[0][3];
  s2 = red[1][0] + red[1][1] + red[1][2] + red[1][3];
  const float mu = s * (1.f / DD);
  const float var = s2 * (1.f / DD) - mu * mu;
  const float inv = rsqrtf(var + 1e-6f);
  bf16* yr = y + (size_t)row * DD;
#pragma unroll
  for (int i = 0; i < 3; ++i) {
    int c = t + i * 256;
    yr[c] = __float2bfloat16((v[i] - mu) * inv * g[c] + b[c]);
  }
}

// ---------------------------------------------------------------------------
// GEMM v3 (r0-proven structure): C[M,N] = A[M,K] @ W[N,K]^T, bf16, f32 accum.
// 128x128 tile, BK=64, 4 waves (2x2), async global_load_lds + XOR swizzle.
// Transposed accumulate (mfma(b,a)): lane holds row = mt*16 + (lane&15),
// cols = nt*16 + quad*4 + r  -> 4 CONSECUTIVE cols -> vectorized epilogue.
// Panel-swizzled rasterization (8 row-tiles per panel) for L2 reuse of W.
// EPI 0: C=bf16 (LDS-retile, 16B stores).  EPI 1: C=fp32 +bias+res (float4).
// EPI 2: C=bf16 +bias +gelu (LDS-retile).
// ---------------------------------------------------------------------------
template <int EPI>
__global__ __launch_bounds__(256, 4)
void gemm_kernel(const bf16* __restrict__ A, const bf16* __restrict__ W,
                 const float* __restrict__ bias, const float* __restrict__ res,
                 void* __restrict__ Cv, int N, int K)
{
  __shared__ __align__(16) short smem[16896];   // 2*8192 K-loop | 128*132 epi
  short* sA = smem;
  short* sB = smem + 8192;

  const int tid  = threadIdx.x;
  const int lane = tid & 63;
  const int wave = tid >> 6;
  const int wm = wave & 1, wn = wave >> 1;
  const int row16 = lane & 15, quad = lane >> 4;

  // panel swizzle: 8 row-tiles per panel (gridDim.y always multiple of 8)
  const int lin = blockIdx.y * gridDim.x + blockIdx.x;
  const int per = gridDim.x * 8;
  const int pan = lin / per, rem = lin % per;
  const int bm = (pan * 8 + (rem & 7)) * 128;
  const int bn = (rem >> 3) * 128;

  const int lrow = lane >> 3;          // 0..7
  const int lkc  = (lane & 7) ^ lrow;  // swizzled chunk

  const bf16* Ag = A + (size_t)(bm + wave * 32 + lrow) * K + lkc * 8;
  const bf16* Bg = W + (size_t)(bn + wave * 32 + lrow) * K + lkc * 8;
  short* sAw = sA + wave * 2048;
  short* sBw = sB + wave * 2048;

  floatx4 acc[4][4] = {};

  for (int kt = 0; kt < K; kt += 64) {
#pragma unroll
    for (int g = 0; g < 4; ++g) {
      async_copy16(Ag + (size_t)g * 8 * K + kt, sAw + g * 512);
      async_copy16(Bg + (size_t)g * 8 * K + kt, sBw + g * 512);
    }
    __syncthreads();
#pragma unroll
    for (int c = 0; c < 2; ++c) {
      short8 af[4], bfr[4];
      const int kc = c * 4 + quad;
#pragma unroll
      for (int mt = 0; mt < 4; ++mt) {
        const int row = wm * 64 + mt * 16 + row16;
        af[mt] = *(const short8*)&sA[(row >> 3) * 512 + ((row & 7) * 8 + (kc ^ (row & 7))) * 8];
      }
#pragma unroll
      for (int nt = 0; nt < 4; ++nt) {
        const int row = wn * 64 + nt * 16 + row16;
        bfr[nt] = *(const short8*)&sB[(row >> 3) * 512 + ((row & 7) * 8 + (kc ^ (row & 7))) * 8];
      }
#pragma unroll
      for (int mt = 0; mt < 4; ++mt)
#pragma unroll
        for (int nt = 0; nt < 4; ++nt)
          acc[mt][nt] = mfma_bf16(bfr[nt], af[mt], acc[mt][nt]);  // C^T trick
    }
    __syncthreads();
  }

  if (EPI == 1) {
    // fp32 out, +bias +res, perfect float4 full-line stores
#pragma unroll
    for (int mt = 0; mt < 4; ++mt) {
      const int row = bm + wm * 64 + mt * 16 + row16;
#pragma unroll
      for (int nt = 0; nt < 4; ++nt) {
        const int col = bn + wn * 64 + nt * 16 + quad * 4;
        const floatx4 bv = *(const floatx4*)&bias[col];
        const floatx4 rv = *(const floatx4*)&res[(size_t)row * N + col];
        floatx4 o;
#pragma unroll
        for (int r = 0; r < 4; ++r) o[r] = acc[mt][nt][r] + bv[r] + rv[r];
        *(floatx4*)&((float*)Cv)[(size_t)row * N + col] = o;
      }
    }
  } else {
    // bf16 out via LDS re-tile (stride 132 shorts), then 16B coalesced stores
    short* sC = smem;
#pragma unroll
    for (int mt = 0; mt < 4; ++mt) {
      const int lr = wm * 64 + mt * 16 + row16;
#pragma unroll
      for (int nt = 0; nt < 4; ++nt) {
        const int lc = wn * 64 + nt * 16 + quad * 4;
        floatx4 bv = {};
        if (EPI == 2) bv = *(const floatx4*)&bias[bn + lc];
        shortx4 pk;
#pragma unroll
        for (int r = 0; r < 4; ++r) {
          float v = acc[mt][nt][r] + bv[r];
          if (EPI == 2) v = gelu_f(v);
          pk[r] = bf16_bits(v);
        }
        *(shortx4*)&sC[lr * 132 + lc] = pk;
      }
    }
    __syncthreads();
#pragma unroll
    for (int it = 0; it < 8; ++it) {
      const int row = (tid >> 4) + it * 16;
      const int col = (tid & 15) * 8;
      short8 v = *(const short8*)&sC[row * 132 + col];
      *(short8*)&((bf16*)Cv)[(size_t)(bm + row) * N + bn + col] = v;
    }
  }
}

// ---------------------------------------------------------------------------
// V transpose: qkv [nb,N,3,H,64] -> Vt [nb*H, 64, N]
// ---------------------------------------------------------------------------
__global__ __launch_bounds__(256)
void vtrans_kernel(const bf16* __restrict__ qkv, bf16* __restrict__ vt)
{
  const int bh = blockIdx.y;
  const int b = bh / HH, h = bh % HH;
  const int n0 = blockIdx.x * 64;
  __shared__ __align__(16) short tile[64 * 72];
  const int tid = threadIdx.x;

  const int r = tid >> 2, c16 = (tid & 3) * 16;
  const bf16* src = qkv + (size_t)(b * NN + n0 + r) * 2304 + 2 * DD + h * 64 + c16;
  *(short8*)&tile[r * 72 + c16]     = *(const short8*)(src);
  *(short8*)&tile[r * 72 + c16 + 8] = *(const short8*)(src + 8);
  __syncthreads();

#pragma unroll
  for (int it = 0; it < 2; ++it) {
    const int d  = (tid >> 3) + it * 32;
    const int jg = (tid & 7) * 8;
    short8 o;
#pragma unroll
    for (int t = 0; t < 8; ++t) ((short*)&o)[t] = tile[(jg + t) * 72 + d];
    *(short8*)&vt[((size_t)bh * 64 + d) * NN + n0 + jg] = o;
  }
}

// ---------------------------------------------------------------------------
// Flash attention v3 (fixed-offset softmax, ones-MFMA row sums, S^T P-writes).
// Block = (b,h) x 128 Q rows; wave owns 32 rows.
// ---------------------------------------------------------------------------
__global__ __launch_bounds__(256, 2)
void attn_kernel(const bf16* __restrict__ qkv, const bf16* __restrict__ vt,
                 bf16* __restrict__ out)
{
  const int bh = blockIdx.y;
  const int b = bh / HH, h = bh % HH;
  const int q0 = blockIdx.x * 128;
  const int tid = threadIdx.x;
  const int lane = tid & 63;
  const int wave = tid >> 6;
  const int row16 = lane & 15, quad = lane >> 4;

  __shared__ __align__(16) short sK[64 * 72];     // [j][d]
  __shared__ __align__(16) short sVt[64 * 72];    // [d][j]
  __shared__ __align__(16) short sP[4][32 * 72];  // per-wave P [q][j]

  const bf16* base  = qkv + (size_t)b * NN * 2304 + h * 64;
  const bf16* vbase = vt + (size_t)bh * 64 * NN;

  short8 qf[2][2];
#pragma unroll
  for (int qg = 0; qg < 2; ++qg) {
    const bf16* qrow = base + (size_t)(q0 + wave * 32 + qg * 16 + row16) * 2304;
    qf[qg][0] = *(const short8*)(qrow + quad * 8);
    qf[qg][1] = *(const short8*)(qrow + 32 + quad * 8);
  }

  floatx4 o_acc[2][4] = {};
  floatx4 l_acc[2] = {};
  const short8 ones = { (short)0x3F80, (short)0x3F80, (short)0x3F80, (short)0x3F80,
                        (short)0x3F80, (short)0x3F80, (short)0x3F80, (short)0x3F80 };

  const int sr = tid >> 2;
  const int sc = (tid & 3) * 16;
  const float ESC = 0.1803368801f;   // log2(e)/8

  for (int jt = 0; jt < NN / 64; ++jt) {
    const int j0 = jt * 64;
    {
      const bf16* kp = base + (size_t)(j0 + sr) * 2304 + DD + sc;
      *(short8*)&sK[sr * 72 + sc]     = *(const short8*)(kp);
      *(short8*)&sK[sr * 72 + sc + 8] = *(const short8*)(kp + 8);
      const bf16* vp = vbase + (size_t)sr * NN + j0 + sc;
      *(short8*)&sVt[sr * 72 + sc]     = *(const short8*)(vp);
      *(short8*)&sVt[sr * 72 + sc + 8] = *(const short8*)(vp + 8);
    }
    __syncthreads();

#pragma unroll
    for (int nt = 0; nt < 4; ++nt) {
      short8 kb0 = *(const short8*)&sK[(nt * 16 + row16) * 72 + quad * 8];
      short8 kb1 = *(const short8*)&sK[(nt * 16 + row16) * 72 + 32 + quad * 8];
#pragma unroll
      for (int qg = 0; qg < 2; ++qg) {
        floatx4 st = {};
        st = mfma_bf16(kb0, qf[qg][0], st);
        st = mfma_bf16(kb1, qf[qg][1], st);
        shortx4 pk;
#pragma unroll
        for (int r = 0; r < 4; ++r)
          pk[r] = bf16_bits(exp2f(fminf(st[r] * ESC, 30.f)));
        *(shortx4*)&sP[wave][(qg * 16 + row16) * 72 + nt * 16 + quad * 4] = pk;
      }
    }

    short8 vb[4][2];
#pragma unroll
    for (int dt = 0; dt < 4; ++dt) {
      vb[dt][0] = *(const short8*)&sVt[(dt * 16 + row16) * 72 + quad * 8];
      vb[dt][1] = *(const short8*)&sVt[(dt * 16 + row16) * 72 + 32 + quad * 8];
    }
#pragma unroll
    for (int qg = 0; qg < 2; ++qg) {
      short8 pf0 = *(const short8*)&sP[wave][(qg * 16 + row16) * 72 + quad * 8];
      short8 pf1 = *(const short8*)&sP[wave][(qg * 16 + row16) * 72 + 32 + quad * 8];
      l_acc[qg] = mfma_bf16(pf0, ones, l_acc[qg]);
      l_acc[qg] = mfma_bf16(pf1, ones, l_acc[qg]);
#pragma unroll
      for (int dt = 0; dt < 4; ++dt) {
        o_acc[qg][dt] = mfma_bf16(pf0, vb[dt][0], o_acc[qg][dt]);
        o_acc[qg][dt] = mfma_bf16(pf1, vb[dt][1], o_acc[qg][dt]);
      }
    }
    __syncthreads();
  }

#pragma unroll
  for (int qg = 0; qg < 2; ++qg) {
#pragma unroll
    for (int r = 0; r < 4; ++r) {
      const float inv = 1.f / l_acc[qg][r];
      const size_t n = (size_t)(b * NN + q0 + wave * 32 + qg * 16 + quad * 4 + r);
#pragma unroll
      for (int dt = 0; dt < 4; ++dt) {
        out[n * DD + h * 64 + dt * 16 + row16] =
            __float2bfloat16(o_acc[qg][dt][r] * inv);
      }
    }
  }
}

// ---------------------------------------------------------------------------
extern "C" void kernel_launch(void* const* d_in, const int* in_sizes, int n_in,
                              void* d_out, int out_size, void* d_ws, size_t ws_size,
                              hipStream_t stream)
{
  const float* x       = (const float*)d_in[0];
  const float* qkv_w   = (const float*)d_in[1];
  const float* proj_w  = (const float*)d_in[2];
  const float* proj_b  = (const float*)d_in[3];
  const float* fc1_w   = (const float*)d_in[4];
  const float* fc1_b   = (const float*)d_in[5];
  const float* fc2_w   = (const float*)d_in[6];
  const float* fc2_b   = (const float*)d_in[7];
  const float* norm1_g = (const float*)d_in[8];
  const float* norm1_b = (const float*)d_in[9];
  const float* norm2_g = (const float*)d_in[10];
  const float* norm2_b = (const float*)d_in[11];
  float* out = (float*)d_out;

  const int M = BB * NN;  // 16384 rows
  char* ws = (char*)d_ws;

  bf16* wq = (bf16*)ws;                                  // [2304,768]
  bf16* wp = wq + (size_t)3 * DD * DD;                   // [768,768]
  bf16* w1 = wp + (size_t)DD * DD;                       // [3072,768]
  bf16* w2 = w1 + (size_t)HID * DD;                      // [768,3072]
  bf16* xn = w2 + (size_t)DD * HID;                      // [M,768] bf16
  char* p2 = (char*)(xn + (size_t)M * DD);
  const size_t base_b = (size_t)(p2 - ws);               // 39,321,600

  int NBc = 1;
  for (int c = 16; c >= 1; c >>= 1)
    if (ws_size >= base_b + (size_t)c * 1024 * 7680) { NBc = c; break; }

  const int Rc = NBc * NN;
  bf16* qkvb = (bf16*)p2;                        // [Rc, 2304]
  bf16* aob  = qkvb + (size_t)Rc * 2304;         // [Rc, 768]
  bf16* vtb  = aob  + (size_t)Rc * DD;           // [NBc*H, 64, N]
  bf16* hb   = (bf16*)p2;                        // [Rc, 3072] (MLP phase)

  cvt_kernel<<<(3 * DD * DD / 4 + 255) / 256, 256, 0, stream>>>(qkv_w, wq, 3 * DD * DD / 4);
  cvt_kernel<<<(DD * DD / 4 + 255) / 256, 256, 0, stream>>>(proj_w, wp, DD * DD / 4);
  cvt_kernel<<<(HID * DD / 4 + 255) / 256, 256, 0, stream>>>(fc1_w, w1, HID * DD / 4);
  cvt_kernel<<<(DD * HID / 4 + 255) / 256, 256, 0, stream>>>(fc2_w, w2, DD * HID / 4);

  ln_kernel<<<M, 256, 0, stream>>>(x, norm1_g, norm1_b, xn);

  for (int c = 0; c < BB / NBc; ++c) {
    const size_t r0 = (size_t)c * Rc;
    gemm_kernel<0><<<dim3(3 * DD / 128, Rc / 128), 256, 0, stream>>>(
        xn + r0 * DD, wq, nullptr, nullptr, qkvb, 3 * DD, DD);
    vtrans_kernel<<<dim3(NN / 64, NBc * HH), 256, 0, stream>>>(qkvb, vtb);
    attn_kernel<<<dim3(NN / 128, NBc * HH), 256, 0, stream>>>(qkvb, vtb, aob);
    gemm_kernel<1><<<dim3(DD / 128, Rc / 128), 256, 0, stream>>>(
        aob, wp, proj_b, x + r0 * DD, out + r0 * DD, DD, DD);
  }

  ln_kernel<<<M, 256, 0, stream>>>(out, norm2_g, norm2_b, xn);

  for (int c = 0; c < BB / NBc; ++c) {
    const size_t r0 = (size_t)c * Rc;
    gemm_kernel<2><<<dim3(HID / 128, Rc / 128), 256, 0, stream>>>(
        xn + r0 * DD, w1, fc1_b, nullptr, hb, HID, DD);
    gemm_kernel<1><<<dim3(DD / 128, Rc / 128), 256, 0, stream>>>(
        hb, w2, fc2_b, out + r0 * DD, out + r0 * DD, DD, HID);
  }
}

// Round 5
// 531.553 us; speedup vs baseline: 2.9958x; 1.0501x over previous
//
#include <hip/hip_runtime.h>
#include <hip/hip_bf16.h>
#include <math.h>

using bf16 = __hip_bfloat16;
typedef __attribute__((ext_vector_type(8))) short short8;
typedef __attribute__((ext_vector_type(4))) short shortx4;
typedef __attribute__((ext_vector_type(4))) float floatx4;

// Problem constants
#define BB 16
#define NN 1024
#define DD 768
#define HH 12
#define HD 64
#define HID 3072

__device__ __forceinline__ floatx4 mfma_bf16(short8 a, short8 b, floatx4 c) {
  return __builtin_amdgcn_mfma_f32_16x16x32_bf16(a, b, c, 0, 0, 0);
}

__device__ __forceinline__ short bf16_bits(float f) {
  union { bf16 h; short s; } u;
  u.h = __float2bfloat16(f);
  return u.s;
}

__device__ __forceinline__ void async_copy16(const void* g, void* l) {
  __builtin_amdgcn_global_load_lds(
      (const __attribute__((address_space(1))) unsigned int*)g,
      (__attribute__((address_space(3))) unsigned int*)l,
      16, 0, 0);
}

// tanh-form gelu via exp2. Passed with identical absmax (0.03125) in prior
// rounds; ~8 VALU ops vs ~40 for erff.
__device__ __forceinline__ float gelu_f(float x) {
  const float z = x * fmaf(0.10294324f, x * x, 2.3022082f);
  const float e = exp2f(z);
  return x - x * __builtin_amdgcn_rcpf(e + 1.0f);
}

// ---------------------------------------------------------------------------
// fp32 -> bf16 conversion (weights), 4 elements/thread.
// ---------------------------------------------------------------------------
__global__ __launch_bounds__(256)
void cvt_kernel(const float* __restrict__ in, bf16* __restrict__ out, int n4)
{
  const int i = blockIdx.x * 256 + threadIdx.x;
  if (i >= n4) return;
  const float4 v = ((const float4*)in)[i];
  shortx4 o;
  o.x = bf16_bits(v.x); o.y = bf16_bits(v.y);
  o.z = bf16_bits(v.z); o.w = bf16_bits(v.w);
  ((shortx4*)out)[i] = o;
}

// ---------------------------------------------------------------------------
// LayerNorm: fp32 in, bf16 out. One block (256 thr) per row of 768.
// ---------------------------------------------------------------------------
__global__ __launch_bounds__(256)
void ln_kernel(const float* __restrict__ x, const float* __restrict__ g,
               const float* __restrict__ b, bf16* __restrict__ y)
{
  const int row = blockIdx.x;
  const int t = threadIdx.x;
  const float* xr = x + (size_t)row * DD;
  float v[3];
  float s = 0.f, s2 = 0.f;
#pragma unroll
  for (int i = 0; i < 3; ++i) {
    float f = xr[t + i * 256];
    v[i] = f;
    s += f;
    s2 += f * f;
  }
#pragma unroll
  for (int off = 1; off < 64; off <<= 1) {
    s  += __shfl_xor(s, off);
    s2 += __shfl_xor(s2, off);
  }
  __shared__ float red[2][4];
  const int wave = t >> 6, lane = t & 63;
  if (lane == 0) { red[0][wave] = s; red[1][wave] = s2; }
  __syncthreads();
  s  = red[0][0] + red[0][1] + red[0][2] + red[0][3];
  s2 = red[1][0] + red[1][1] + red[1][2] + red[1][3];
  const float mu = s * (1.f / DD);
  const float var = s2 * (1.f / DD) - mu * mu;
  const float inv = rsqrtf(var + 1e-6f);
  bf16* yr = y + (size_t)row * DD;
#pragma unroll
  for (int i = 0; i < 3; ++i) {
    int c = t + i * 256;
    yr[c] = __float2bfloat16((v[i] - mu) * inv * g[c] + b[c]);
  }
}

// ---------------------------------------------------------------------------
// GEMM v3 (r0-proven structure): C[M,N] = A[M,K] @ W[N,K]^T, bf16, f32 accum.
// 128x128 tile, BK=64, 4 waves (2x2), async global_load_lds + XOR swizzle.
// ---------------------------------------------------------------------------
template <int EPI>
__global__ __launch_bounds__(256, 4)
void gemm_kernel(const bf16* __restrict__ A, const bf16* __restrict__ W,
                 const float* __restrict__ bias, const float* __restrict__ res,
                 void* __restrict__ Cv, int N, int K)
{
  __shared__ __align__(16) short smem[16896];   // 2*8192 K-loop | 128*132 epi
  short* sA = smem;
  short* sB = smem + 8192;

  const int tid  = threadIdx.x;
  const int lane = tid & 63;
  const int wave = tid >> 6;
  const int wm = wave & 1, wn = wave >> 1;
  const int row16 = lane & 15, quad = lane >> 4;

  // panel swizzle: 8 row-tiles per panel (gridDim.y always multiple of 8)
  const int lin = blockIdx.y * gridDim.x + blockIdx.x;
  const int per = gridDim.x * 8;
  const int pan = lin / per, rem = lin % per;
  const int bm = (pan * 8 + (rem & 7)) * 128;
  const int bn = (rem >> 3) * 128;

  const int lrow = lane >> 3;          // 0..7
  const int lkc  = (lane & 7) ^ lrow;  // swizzled chunk

  const bf16* Ag = A + (size_t)(bm + wave * 32 + lrow) * K + lkc * 8;
  const bf16* Bg = W + (size_t)(bn + wave * 32 + lrow) * K + lkc * 8;
  short* sAw = sA + wave * 2048;
  short* sBw = sB + wave * 2048;

  floatx4 acc[4][4] = {};

  for (int kt = 0; kt < K; kt += 64) {
#pragma unroll
    for (int g = 0; g < 4; ++g) {
      async_copy16(Ag + (size_t)g * 8 * K + kt, sAw + g * 512);
      async_copy16(Bg + (size_t)g * 8 * K + kt, sBw + g * 512);
    }
    __syncthreads();
#pragma unroll
    for (int c = 0; c < 2; ++c) {
      short8 af[4], bfr[4];
      const int kc = c * 4 + quad;
#pragma unroll
      for (int mt = 0; mt < 4; ++mt) {
        const int row = wm * 64 + mt * 16 + row16;
        af[mt] = *(const short8*)&sA[(row >> 3) * 512 + ((row & 7) * 8 + (kc ^ (row & 7))) * 8];
      }
#pragma unroll
      for (int nt = 0; nt < 4; ++nt) {
        const int row = wn * 64 + nt * 16 + row16;
        bfr[nt] = *(const short8*)&sB[(row >> 3) * 512 + ((row & 7) * 8 + (kc ^ (row & 7))) * 8];
      }
#pragma unroll
      for (int mt = 0; mt < 4; ++mt)
#pragma unroll
        for (int nt = 0; nt < 4; ++nt)
          acc[mt][nt] = mfma_bf16(bfr[nt], af[mt], acc[mt][nt]);  // C^T trick
    }
    __syncthreads();
  }

  if (EPI == 1) {
    // fp32 out, +bias +res, perfect float4 full-line stores
#pragma unroll
    for (int mt = 0; mt < 4; ++mt) {
      const int row = bm + wm * 64 + mt * 16 + row16;
#pragma unroll
      for (int nt = 0; nt < 4; ++nt) {
        const int col = bn + wn * 64 + nt * 16 + quad * 4;
        const floatx4 bv = *(const floatx4*)&bias[col];
        const floatx4 rv = *(const floatx4*)&res[(size_t)row * N + col];
        floatx4 o;
#pragma unroll
        for (int r = 0; r < 4; ++r) o[r] = acc[mt][nt][r] + bv[r] + rv[r];
        *(floatx4*)&((float*)Cv)[(size_t)row * N + col] = o;
      }
    }
  } else {
    // bf16 out via LDS re-tile (stride 132 shorts), then 16B coalesced stores
    short* sC = smem;
#pragma unroll
    for (int mt = 0; mt < 4; ++mt) {
      const int lr = wm * 64 + mt * 16 + row16;
#pragma unroll
      for (int nt = 0; nt < 4; ++nt) {
        const int lc = wn * 64 + nt * 16 + quad * 4;
        floatx4 bv = {};
        if (EPI == 2) bv = *(const floatx4*)&bias[bn + lc];
        shortx4 pk;
#pragma unroll
        for (int r = 0; r < 4; ++r) {
          float v = acc[mt][nt][r] + bv[r];
          if (EPI == 2) v = gelu_f(v);
          pk[r] = bf16_bits(v);
        }
        *(shortx4*)&sC[lr * 132 + lc] = pk;
      }
    }
    __syncthreads();
#pragma unroll
    for (int it = 0; it < 8; ++it) {
      const int row = (tid >> 4) + it * 16;
      const int col = (tid & 15) * 8;
      short8 v = *(const short8*)&sC[row * 132 + col];
      *(short8*)&((bf16*)Cv)[(size_t)(bm + row) * N + bn + col] = v;
    }
  }
}

// ---------------------------------------------------------------------------
// V transpose: qkv [nb,N,3,H,64] -> Vt [nb*H, 64, N]
// ---------------------------------------------------------------------------
__global__ __launch_bounds__(256)
void vtrans_kernel(const bf16* __restrict__ qkv, bf16* __restrict__ vt)
{
  const int bh = blockIdx.y;
  const int b = bh / HH, h = bh % HH;
  const int n0 = blockIdx.x * 64;
  __shared__ __align__(16) short tile[64 * 72];
  const int tid = threadIdx.x;

  const int r = tid >> 2, c16 = (tid & 3) * 16;
  const bf16* src = qkv + (size_t)(b * NN + n0 + r) * 2304 + 2 * DD + h * 64 + c16;
  *(short8*)&tile[r * 72 + c16]     = *(const short8*)(src);
  *(short8*)&tile[r * 72 + c16 + 8] = *(const short8*)(src + 8);
  __syncthreads();

#pragma unroll
  for (int it = 0; it < 2; ++it) {
    const int d  = (tid >> 3) + it * 32;
    const int jg = (tid & 7) * 8;
    short8 o;
#pragma unroll
    for (int t = 0; t < 8; ++t) ((short*)&o)[t] = tile[(jg + t) * 72 + d];
    *(short8*)&vt[((size_t)bh * 64 + d) * NN + n0 + jg] = o;
  }
}

// ---------------------------------------------------------------------------
// Flash attention v4: 256 Q rows per block (wave owns 64), fragment-order LDS
// (conflict-free by construction, proven in GEMM r2: conflicts = 0), async
// global_load_lds staging with DMA-under-compute prefetch.
//
// sK/sVt: 8 fragments x 1KB each; frag f read densely at f*1KB + lane*16B.
// Wave w DMA-stages frags (nt=w, dh=0/1) of K and (dt=w, jh=0/1) of Vt; the
// fragment permutation rides on the per-lane GLOBAL address (rows strided
// >=2KB, scatter legal for global_load_lds sources).
//
// sP per (wave,qg): 2KB j-fragment-order [j>>3][q][j&7]. QK write lands 4
// dwords/bank (balanced = min phases); PV read is dense lane*16B.
//
// Per jt: {barrier (vmcnt drain -> tiles valid); ds_read kb/vb to regs;
// barrier (reads retired chip-wide); issue DMA for jt+1 (lands under
// compute); QK + exp2 -> sP; PV + ones-MFMA row sums}.
// ---------------------------------------------------------------------------
__global__ __launch_bounds__(256, 2)
void attn_kernel(const bf16* __restrict__ qkv, const bf16* __restrict__ vt,
                 bf16* __restrict__ out)
{
  const int bh = blockIdx.y;
  const int b = bh / HH, h = bh % HH;
  const int q0 = blockIdx.x * 256;
  const int tid = threadIdx.x;
  const int lane = tid & 63;
  const int wave = tid >> 6;
  const int row16 = lane & 15, quad = lane >> 4;

  __shared__ __align__(16) short sK[4096];        // 8 x 1KB frags [nt][dh]
  __shared__ __align__(16) short sVt[4096];       // 8 x 1KB frags [dt][jh]
  __shared__ __align__(16) short sP[4][4][1024];  // [wave][qg] j-frag order

  const bf16* base  = qkv + (size_t)b * NN * 2304 + h * 64;
  const bf16* vbase = vt + (size_t)bh * 64 * NN;

  // Q fragments: 4 qg x 2 d-halves (wave owns q rows wave*64 .. +63)
  short8 qf[4][2];
#pragma unroll
  for (int qg = 0; qg < 4; ++qg) {
    const bf16* qrow = base + (size_t)(q0 + wave * 64 + qg * 16 + row16) * 2304;
    qf[qg][0] = *(const short8*)(qrow + quad * 8);
    qf[qg][1] = *(const short8*)(qrow + 32 + quad * 8);
  }

  floatx4 o_acc[4][4] = {};
  floatx4 l_acc[4] = {};
  const short8 ones = { (short)0x3F80, (short)0x3F80, (short)0x3F80, (short)0x3F80,
                        (short)0x3F80, (short)0x3F80, (short)0x3F80, (short)0x3F80 };

  // staging sources (fragment permutation on global address); wave w owns
  // K-frag nt=w and V-frag dt=w (both halves).
  const bf16* ksrc = base + DD + (size_t)(wave * 16 + row16) * 2304 + quad * 8;
  const bf16* vsrc = vbase + (size_t)(wave * 16 + row16) * NN + quad * 8;
  short* kdst = sK + wave * 1024 + lane * 8;
  short* vdst = sVt + wave * 1024 + lane * 8;

  // prologue: stage jt = 0
  async_copy16(ksrc, kdst);
  async_copy16(ksrc + 32, kdst + 512);
  async_copy16(vsrc, vdst);
  async_copy16(vsrc + 32, vdst + 512);

  const float ESC = 0.1803368801f;   // log2(e)/8

  for (int jt = 0; jt < NN / 64; ++jt) {
    __syncthreads();               // drains vmcnt -> staged tiles valid

    short8 vb[4][2];
#pragma unroll
    for (int dt = 0; dt < 4; ++dt) {
      vb[dt][0] = *(const short8*)&sVt[dt * 1024 + lane * 8];
      vb[dt][1] = *(const short8*)&sVt[dt * 1024 + 512 + lane * 8];
    }
    short8 kb[4][2];
#pragma unroll
    for (int nt = 0; nt < 4; ++nt) {
      kb[nt][0] = *(const short8*)&sK[nt * 1024 + lane * 8];
      kb[nt][1] = *(const short8*)&sK[nt * 1024 + 512 + lane * 8];
    }
    __syncthreads();               // all frag reads retired -> safe to restage

    if (jt + 1 < NN / 64) {        // DMA for jt+1 lands under compute below
      const bf16* k2 = ksrc + (size_t)(jt + 1) * 64 * 2304;
      const bf16* v2 = vsrc + (jt + 1) * 64;
      async_copy16(k2, kdst);
      async_copy16(k2 + 32, kdst + 512);
      async_copy16(v2, vdst);
      async_copy16(v2 + 32, vdst + 512);
    }

    // QK^T + exp2 -> sP (fragment order). Output of mfma(kb,qf): lane holds
    // q = qg*16 + row16 side? no: lane&15 = q-row of second arg... per C^T
    // convention lane holds q = (via store) rows quad*4+r = j, row16 = q.
#pragma unroll
    for (int nt = 0; nt < 4; ++nt) {
#pragma unroll
      for (int qg = 0; qg < 4; ++qg) {
        floatx4 st = {};
        st = mfma_bf16(kb[nt][0], qf[qg][0], st);
        st = mfma_bf16(kb[nt][1], qf[qg][1], st);
        shortx4 pk;
#pragma unroll
        for (int r = 0; r < 4; ++r)
          pk[r] = bf16_bits(exp2f(fminf(st[r] * ESC, 30.f)));
        // P[q=row16][j = nt*16 + quad*4 + r] -> frag addr
        *(shortx4*)&sP[wave][qg][(row16 + 16 * (2 * nt + (quad >> 1))) * 8 +
                                 (quad & 1) * 4] = pk;
      }
    }

    // PV + row sums (dense fragment reads, per-wave -> no barrier needed;
    // compiler orders ds_write->ds_read via lgkmcnt)
#pragma unroll
    for (int qg = 0; qg < 4; ++qg) {
      const short8 pf0 = *(const short8*)&sP[wave][qg][lane * 8];
      const short8 pf1 = *(const short8*)&sP[wave][qg][512 + lane * 8];
      l_acc[qg] = mfma_bf16(pf0, ones, l_acc[qg]);
      l_acc[qg] = mfma_bf16(pf1, ones, l_acc[qg]);
#pragma unroll
      for (int dt = 0; dt < 4; ++dt) {
        o_acc[qg][dt] = mfma_bf16(pf0, vb[dt][0], o_acc[qg][dt]);
        o_acc[qg][dt] = mfma_bf16(pf1, vb[dt][1], o_acc[qg][dt]);
      }
    }
  }

#pragma unroll
  for (int qg = 0; qg < 4; ++qg) {
#pragma unroll
    for (int r = 0; r < 4; ++r) {
      const float inv = 1.f / l_acc[qg][r];
      const size_t n = (size_t)(b * NN + q0 + wave * 64 + qg * 16 + quad * 4 + r);
#pragma unroll
      for (int dt = 0; dt < 4; ++dt) {
        out[n * DD + h * 64 + dt * 16 + row16] =
            __float2bfloat16(o_acc[qg][dt][r] * inv);
      }
    }
  }
}

// ---------------------------------------------------------------------------
extern "C" void kernel_launch(void* const* d_in, const int* in_sizes, int n_in,
                              void* d_out, int out_size, void* d_ws, size_t ws_size,
                              hipStream_t stream)
{
  const float* x       = (const float*)d_in[0];
  const float* qkv_w   = (const float*)d_in[1];
  const float* proj_w  = (const float*)d_in[2];
  const float* proj_b  = (const float*)d_in[3];
  const float* fc1_w   = (const float*)d_in[4];
  const float* fc1_b   = (const float*)d_in[5];
  const float* fc2_w   = (const float*)d_in[6];
  const float* fc2_b   = (const float*)d_in[7];
  const float* norm1_g = (const float*)d_in[8];
  const float* norm1_b = (const float*)d_in[9];
  const float* norm2_g = (const float*)d_in[10];
  const float* norm2_b = (const float*)d_in[11];
  float* out = (float*)d_out;

  const int M = BB * NN;  // 16384 rows
  char* ws = (char*)d_ws;

  bf16* wq = (bf16*)ws;                                  // [2304,768]
  bf16* wp = wq + (size_t)3 * DD * DD;                   // [768,768]
  bf16* w1 = wp + (size_t)DD * DD;                       // [3072,768]
  bf16* w2 = w1 + (size_t)HID * DD;                      // [768,3072]
  bf16* xn = w2 + (size_t)DD * HID;                      // [M,768] bf16
  char* p2 = (char*)(xn + (size_t)M * DD);
  const size_t base_b = (size_t)(p2 - ws);               // 39,321,600

  int NBc = 1;
  for (int c = 16; c >= 1; c >>= 1)
    if (ws_size >= base_b + (size_t)c * 1024 * 7680) { NBc = c; break; }

  const int Rc = NBc * NN;
  bf16* qkvb = (bf16*)p2;                        // [Rc, 2304]
  bf16* aob  = qkvb + (size_t)Rc * 2304;         // [Rc, 768]
  bf16* vtb  = aob  + (size_t)Rc * DD;           // [NBc*H, 64, N]
  bf16* hb   = (bf16*)p2;                        // [Rc, 3072] (MLP phase)

  cvt_kernel<<<(3 * DD * DD / 4 + 255) / 256, 256, 0, stream>>>(qkv_w, wq, 3 * DD * DD / 4);
  cvt_kernel<<<(DD * DD / 4 + 255) / 256, 256, 0, stream>>>(proj_w, wp, DD * DD / 4);
  cvt_kernel<<<(HID * DD / 4 + 255) / 256, 256, 0, stream>>>(fc1_w, w1, HID * DD / 4);
  cvt_kernel<<<(DD * HID / 4 + 255) / 256, 256, 0, stream>>>(fc2_w, w2, DD * HID / 4);

  ln_kernel<<<M, 256, 0, stream>>>(x, norm1_g, norm1_b, xn);

  for (int c = 0; c < BB / NBc; ++c) {
    const size_t r0 = (size_t)c * Rc;
    gemm_kernel<0><<<dim3(3 * DD / 128, Rc / 128), 256, 0, stream>>>(
        xn + r0 * DD, wq, nullptr, nullptr, qkvb, 3 * DD, DD);
    vtrans_kernel<<<dim3(NN / 64, NBc * HH), 256, 0, stream>>>(qkvb, vtb);
    attn_kernel<<<dim3(NN / 256, NBc * HH), 256, 0, stream>>>(qkvb, vtb, aob);
    gemm_kernel<1><<<dim3(DD / 128, Rc / 128), 256, 0, stream>>>(
        aob, wp, proj_b, x + r0 * DD, out + r0 * DD, DD, DD);
  }

  ln_kernel<<<M, 256, 0, stream>>>(out, norm2_g, norm2_b, xn);

  for (int c = 0; c < BB / NBc; ++c) {
    const size_t r0 = (size_t)c * Rc;
    gemm_kernel<2><<<dim3(HID / 128, Rc / 128), 256, 0, stream>>>(
        xn + r0 * DD, w1, fc1_b, nullptr, hb, HID, DD);
    gemm_kernel<1><<<dim3(DD / 128, Rc / 128), 256, 0, stream>>>(
        hb, w2, fc2_b, out + r0 * DD, out + r0 * DD, DD, HID);
  }
}